// Round 6
// baseline (2589.158 us; speedup 1.0000x reference)
//
#include <hip/hip_runtime.h>
#include <hip/hip_bf16.h>
#include <stdint.h>

typedef short bf16x8 __attribute__((ext_vector_type(8)));
typedef float f32x4  __attribute__((ext_vector_type(4)));
typedef unsigned int u32x4 __attribute__((ext_vector_type(4)));

static __device__ __forceinline__ unsigned short bf16_rne(float f) {
    unsigned u = __builtin_bit_cast(unsigned, f);
    unsigned r = u + 0x7fffu + ((u >> 16) & 1u);
    return (unsigned short)(r >> 16);
}
static __device__ __forceinline__ float bf16tof(unsigned short h) {
    unsigned u = ((unsigned)h) << 16;
    return __builtin_bit_cast(float, u);
}

// ---------------- K1: transpose + convert W_xh [K][N] f32 -> Wt [N][K] bf16 ---
__global__ __launch_bounds__(256) void k_transpose(const float* __restrict__ W,
                                                   unsigned short* __restrict__ Wt) {
    __shared__ float tile[64][65];
    int bx = blockIdx.x & 15, by = blockIdx.x >> 4;
    int n0 = bx * 64, k0 = by * 64;
    int tx = threadIdx.x & 63, ty = threadIdx.x >> 6;
#pragma unroll
    for (int p = 0; p < 16; ++p) {
        int r = p * 4 + ty;
        tile[r][tx] = W[(size_t)(k0 + r) * 1024 + n0 + tx];
    }
    __syncthreads();
#pragma unroll
    for (int p = 0; p < 16; ++p) {
        int r = p * 4 + ty;
        Wt[(size_t)(n0 + r) * 1024 + k0 + tx] = bf16_rne(tile[tx][r]);
    }
}

// ---------------- K2: Xp = X @ W_xh + b_h  (bf16 MFMA, 128x128x32 tiles) ------
#define LDA 80

__global__ __launch_bounds__(256) void k_xpgemm(const float* __restrict__ X,
                                                const unsigned short* __restrict__ Wt,
                                                const float* __restrict__ bh,
                                                unsigned short* __restrict__ Xp) {
    __shared__ __align__(16) unsigned char ldsA[128 * LDA];
    __shared__ __align__(16) unsigned char ldsB[128 * LDA];
    int p = blockIdx.x;
    int lo = (p & 7) * 256 + (p >> 3);
    int mt = lo >> 3, nt = lo & 7;
    int m0 = mt * 128, n0 = nt * 128;
    int tid = threadIdx.x;
    int lane = tid & 63, wid = tid >> 6;
    int wr = wid >> 1, wc = wid & 1;
    int mw = wr * 64, nw = wc * 64;
    int l15 = lane & 15, kg = lane >> 4;

    f32x4 acc[4][4] = {};
    int arow = tid >> 3, as = tid & 7;
    int brow = tid >> 2, bs = tid & 3;

    for (int kt = 0; kt < 32; ++kt) {
#pragma unroll
        for (int pp = 0; pp < 4; ++pp) {
            int r = pp * 32 + arow;
            const float4 v = *(const float4*)(X + (size_t)(m0 + r) * 1024 + kt * 32 + as * 4);
            unsigned lo32 = ((unsigned)bf16_rne(v.y) << 16) | bf16_rne(v.x);
            unsigned hi32 = ((unsigned)bf16_rne(v.w) << 16) | bf16_rne(v.z);
            *(uint2*)(ldsA + r * LDA + as * 8) = make_uint2(lo32, hi32);
        }
#pragma unroll
        for (int pp = 0; pp < 2; ++pp) {
            int r = pp * 64 + brow;
            uint4 v = *(const uint4*)(Wt + (size_t)(n0 + r) * 1024 + kt * 32 + bs * 8);
            *(uint4*)(ldsB + r * LDA + bs * 16) = v;
        }
        __syncthreads();
        bf16x8 af[4];
#pragma unroll
        for (int i = 0; i < 4; ++i)
            af[i] = *(const bf16x8*)(ldsA + (mw + 16 * i + l15) * LDA + kg * 16);
#pragma unroll
        for (int j = 0; j < 4; ++j) {
            bf16x8 bfj = *(const bf16x8*)(ldsB + (nw + 16 * j + l15) * LDA + kg * 16);
#pragma unroll
            for (int i = 0; i < 4; ++i)
                acc[i][j] = __builtin_amdgcn_mfma_f32_16x16x32_bf16(af[i], bfj, acc[i][j], 0, 0, 0);
        }
        __syncthreads();
    }
#pragma unroll
    for (int j = 0; j < 4; ++j) {
        int col = n0 + nw + 16 * j + l15;
        float bias = bh[col];
#pragma unroll
        for (int i = 0; i < 4; ++i) {
            int rb = m0 + mw + 16 * i + kg * 4;
#pragma unroll
            for (int r = 0; r < 4; ++r)
                Xp[(size_t)(rb + r) * 1024 + col] = bf16_rne(acc[i][j][r] + bias);
        }
    }
}

// ---------------- K3: scan. Round-2-PROVEN flag+ack protocol, rescheduled. ----
#define SB0 __builtin_amdgcn_sched_barrier(0)
#define WAITV0 asm volatile("s_waitcnt vmcnt(0)" ::: "memory")
#define WAITV4 asm volatile("s_waitcnt vmcnt(4)" ::: "memory")

#define LDT(d, a, O) asm volatile("global_load_dwordx4 %0, %1, off offset:" #O " sc0 sc1" : "=v"(d) : "v"(a) : "memory")
#define LDU(d, a, O) asm volatile("global_load_ushort %0, %1, off offset:" #O : "=v"(d) : "v"(a) : "memory")
#define STS(a, v, O) asm volatile("global_store_short %0, %1, off offset:" #O " sc0 sc1" :: "v"(a), "v"(v) : "memory")
#define STD(a, v, O) asm volatile("global_store_dword %0, %1, off offset:" #O " sc0 sc1" :: "v"(a), "v"(v) : "memory")

// 32 x 16B h-loads: row (b0+l15), cols kg*8 + 32*n  (64B byte-stride)
#define ISSUE32H(B, A) do { \
    LDT(B[0],(A),0);     LDT(B[1],(A),64);    LDT(B[2],(A),128);   LDT(B[3],(A),192);   \
    LDT(B[4],(A),256);   LDT(B[5],(A),320);   LDT(B[6],(A),384);   LDT(B[7],(A),448);   \
    LDT(B[8],(A),512);   LDT(B[9],(A),576);   LDT(B[10],(A),640);  LDT(B[11],(A),704);  \
    LDT(B[12],(A),768);  LDT(B[13],(A),832);  LDT(B[14],(A),896);  LDT(B[15],(A),960);  \
    LDT(B[16],(A),1024); LDT(B[17],(A),1088); LDT(B[18],(A),1152); LDT(B[19],(A),1216); \
    LDT(B[20],(A),1280); LDT(B[21],(A),1344); LDT(B[22],(A),1408); LDT(B[23],(A),1472); \
    LDT(B[24],(A),1536); LDT(B[25],(A),1600); LDT(B[26],(A),1664); LDT(B[27],(A),1728); \
    LDT(B[28],(A),1792); LDT(B[29],(A),1856); LDT(B[30],(A),1920); LDT(B[31],(A),1984); } while (0)

__global__ __launch_bounds__(64, 1) void k_scan(const float* __restrict__ Whh,
                                                const unsigned short* __restrict__ Xp,
                                                unsigned short* __restrict__ hbuf, // [2][64][1024] bf16
                                                unsigned int* flags,               // [256]
                                                float* __restrict__ out) {
    const int wid = blockIdx.x;    // 0..255
    const int rt = wid >> 6, ct = wid & 63;
    const int j0 = ct * 16, b0 = rt * 16;
    const int lane = threadIdx.x;
    const int l15 = lane & 15, kg = lane >> 4;
    const int jj = j0 + l15;
    const int rbase = b0 + kg * 4;

    // W_hh column-slice in registers (round-2-proven plain loads; AGPR-eligible)
    bf16x8 w[32];
#pragma unroll
    for (int i = 0; i < 32; ++i) {
#pragma unroll
        for (int e = 0; e < 8; ++e)
            w[i][e] = (short)bf16_rne(Whh[(size_t)(i * 32 + kg * 8 + e) * 1024 + jj]);
    }

    const uint64_t fp = (uint64_t)(flags + rt * 64 + lane);   // 1 flag per lane
    const uint64_t myflag = (uint64_t)(flags + wid);
    const uint64_t hrd = (uint64_t)hbuf + (uint64_t)(b0 + l15) * 2048 + kg * 16;
    const uint64_t hwr = (uint64_t)hbuf + (uint64_t)rbase * 2048 + (uint64_t)jj * 2;
    const uint64_t xb  = (uint64_t)Xp + (uint64_t)(rbase * 1024 + jj) * 2;

    u32x4 hr[32];
    unsigned xr[4];
    float hv[4];

    for (int t = 0; t < 512; ++t) {
        // ---- wait for all 64 producers of this row group (proven handshake) --
        if (t > 0) {
            unsigned tt = (unsigned)t;
            for (;;) {
                unsigned f;
                asm volatile("global_load_dword %0, %1, off sc0 sc1\n\t"
                             "s_waitcnt vmcnt(0)"
                             : "=v"(f) : "v"(fp) : "memory");
                if (__all((int)(f >= tt))) break;
            }
        }
        SB0;

        // ---- issue h loads (32x16B, IF-coherent), then xp loads (HBM/L2) -----
        const uint64_t hp = hrd + ((uint64_t)(t & 1) << 17);
        ISSUE32H(hr, hp);
        const uint64_t xa = xb + (uint64_t)t * 131072;
        LDU(xr[0], xa, 0); LDU(xr[1], xa, 2048);
        LDU(xr[2], xa + 4096, 0); LDU(xr[3], xa + 4096, 2048);

        WAITV4; SB0;                        // 32 h loads retired; xp still flying

        // ---- MFMA (round-2 exact order: 4 independent chains) ----------------
        f32x4 a0 = {0.f, 0.f, 0.f, 0.f}, a1 = {0.f, 0.f, 0.f, 0.f};
        f32x4 a2 = {0.f, 0.f, 0.f, 0.f}, a3 = {0.f, 0.f, 0.f, 0.f};
#pragma unroll
        for (int ks = 0; ks < 8; ++ks) {
            a0 = __builtin_amdgcn_mfma_f32_16x16x32_bf16(
                __builtin_bit_cast(bf16x8, hr[4 * ks + 0]), w[4 * ks + 0], a0, 0, 0, 0);
            a1 = __builtin_amdgcn_mfma_f32_16x16x32_bf16(
                __builtin_bit_cast(bf16x8, hr[4 * ks + 1]), w[4 * ks + 1], a1, 0, 0, 0);
            a2 = __builtin_amdgcn_mfma_f32_16x16x32_bf16(
                __builtin_bit_cast(bf16x8, hr[4 * ks + 2]), w[4 * ks + 2], a2, 0, 0, 0);
            a3 = __builtin_amdgcn_mfma_f32_16x16x32_bf16(
                __builtin_bit_cast(bf16x8, hr[4 * ks + 3]), w[4 * ks + 3], a3, 0, 0, 0);
        }
        f32x4 acc = (a0 + a1) + (a2 + a3);

        WAITV0; SB0;                        // xp retired (hidden under MFMAs)

        // ---- tanh ------------------------------------------------------------
        unsigned hb[4];
#pragma unroll
        for (int r = 0; r < 4; ++r) {
            float z = acc[r] + bf16tof((unsigned short)xr[r]);
            z = fminf(fmaxf(z, -15.f), 15.f);
            float e = __expf(2.f * z);
            float v = (e - 1.f) / (e + 1.f);
            hv[r] = v;
            hb[r] = (unsigned)bf16_rne(v);
        }

        // ---- publish: h stores -> clean ack -> flag (round-2-proven order) ---
        if (t < 511) {
            const uint64_t hn = hwr + ((uint64_t)((t + 1) & 1) << 17);
            STS(hn, hb[0], 0); STS(hn + 2048, hb[1], 0);
            STS(hn + 4096, hb[2], 0); STS(hn + 6144, hb[3], 0);
            WAITV0;                          // only the 4 h-stores outstanding
            if (lane == 0)
                STD(myflag, (unsigned)(t + 1), 0);
        }

        // ---- out stores: off the critical path (plain cached) ----------------
#pragma unroll
        for (int r = 0; r < 4; ++r)
            out[(size_t)(t * 64 + rbase + r) * 1024 + jj] = hv[r];
    }
#pragma unroll
    for (int r = 0; r < 4; ++r)
        out[(size_t)33554432 + (size_t)(rbase + r) * 1024 + jj] = hv[r];
}

// ---------------- launcher ---------------------------------------------------
extern "C" void kernel_launch(void* const* d_in, const int* in_sizes, int n_in,
                              void* d_out, int out_size, void* d_ws, size_t ws_size,
                              hipStream_t stream) {
    const float* X   = (const float*)d_in[0];
    const float* Wxh = (const float*)d_in[1];
    const float* Whh = (const float*)d_in[2];
    const float* bh  = (const float*)d_in[3];
    float* out = (float*)d_out;
    unsigned char* ws = (unsigned char*)d_ws;

    // workspace layout (bytes), high-water 69,469,184 (round-2-proven):
    //   [0)         Wt    : 2 MB   (W_xh^T bf16)
    //   [2097152)   Xp    : 64 MB  (bf16 [T*B][H])
    //   [69206016)  hbuf  : 256 KB (bf16 [2][64][1024])
    //   [69468160)  flags : 1 KB   (u32 [256])
    unsigned short* Wt    = (unsigned short*)(ws);
    unsigned short* Xp    = (unsigned short*)(ws + 2097152);
    unsigned short* hbuf  = (unsigned short*)(ws + 69206016);
    unsigned int*   flags = (unsigned int*)(ws + 69468160);

    hipMemsetAsync(ws + 69206016, 0, 263168, stream);   // h(0)=0, flags=0
    hipLaunchKernelGGL(k_transpose, dim3(256), dim3(256), 0, stream, Wxh, Wt);
    hipLaunchKernelGGL(k_xpgemm, dim3(2048), dim3(256), 0, stream, X, Wt, bh, Xp);
    hipLaunchKernelGGL(k_scan, dim3(256), dim3(64), 0, stream, Whh, Xp, hbuf, flags, out);
}

// Round 7
// 2582.042 us; speedup vs baseline: 1.0028x; 1.0028x over previous
//
#include <hip/hip_runtime.h>
#include <hip/hip_bf16.h>
#include <stdint.h>

typedef short bf16x8 __attribute__((ext_vector_type(8)));
typedef float f32x4  __attribute__((ext_vector_type(4)));
typedef unsigned int u32x4 __attribute__((ext_vector_type(4)));

static __device__ __forceinline__ unsigned short bf16_rne(float f) {
    unsigned u = __builtin_bit_cast(unsigned, f);
    unsigned r = u + 0x7fffu + ((u >> 16) & 1u);
    return (unsigned short)(r >> 16);
}
static __device__ __forceinline__ float bf16tof(unsigned short h) {
    unsigned u = ((unsigned)h) << 16;
    return __builtin_bit_cast(float, u);
}

// ---------------- K1: transpose + convert W_xh [K][N] f32 -> Wt [N][K] bf16 ---
__global__ __launch_bounds__(256) void k_transpose(const float* __restrict__ W,
                                                   unsigned short* __restrict__ Wt) {
    __shared__ float tile[64][65];
    int bx = blockIdx.x & 15, by = blockIdx.x >> 4;
    int n0 = bx * 64, k0 = by * 64;
    int tx = threadIdx.x & 63, ty = threadIdx.x >> 6;
#pragma unroll
    for (int p = 0; p < 16; ++p) {
        int r = p * 4 + ty;
        tile[r][tx] = W[(size_t)(k0 + r) * 1024 + n0 + tx];
    }
    __syncthreads();
#pragma unroll
    for (int p = 0; p < 16; ++p) {
        int r = p * 4 + ty;
        Wt[(size_t)(n0 + r) * 1024 + k0 + tx] = bf16_rne(tile[tx][r]);
    }
}

// ---------------- K2: Xp = X @ W_xh + b_h  (bf16 MFMA, 128x128x32 tiles) ------
#define LDA 80

__global__ __launch_bounds__(256) void k_xpgemm(const float* __restrict__ X,
                                                const unsigned short* __restrict__ Wt,
                                                const float* __restrict__ bh,
                                                unsigned short* __restrict__ Xp) {
    __shared__ __align__(16) unsigned char ldsA[128 * LDA];
    __shared__ __align__(16) unsigned char ldsB[128 * LDA];
    int p = blockIdx.x;
    int lo = (p & 7) * 256 + (p >> 3);
    int mt = lo >> 3, nt = lo & 7;
    int m0 = mt * 128, n0 = nt * 128;
    int tid = threadIdx.x;
    int lane = tid & 63, wid = tid >> 6;
    int wr = wid >> 1, wc = wid & 1;
    int mw = wr * 64, nw = wc * 64;
    int l15 = lane & 15, kg = lane >> 4;

    f32x4 acc[4][4] = {};
    int arow = tid >> 3, as = tid & 7;
    int brow = tid >> 2, bs = tid & 3;

    for (int kt = 0; kt < 32; ++kt) {
#pragma unroll
        for (int pp = 0; pp < 4; ++pp) {
            int r = pp * 32 + arow;
            const float4 v = *(const float4*)(X + (size_t)(m0 + r) * 1024 + kt * 32 + as * 4);
            unsigned lo32 = ((unsigned)bf16_rne(v.y) << 16) | bf16_rne(v.x);
            unsigned hi32 = ((unsigned)bf16_rne(v.w) << 16) | bf16_rne(v.z);
            *(uint2*)(ldsA + r * LDA + as * 8) = make_uint2(lo32, hi32);
        }
#pragma unroll
        for (int pp = 0; pp < 2; ++pp) {
            int r = pp * 64 + brow;
            uint4 v = *(const uint4*)(Wt + (size_t)(n0 + r) * 1024 + kt * 32 + bs * 8);
            *(uint4*)(ldsB + r * LDA + bs * 16) = v;
        }
        __syncthreads();
        bf16x8 af[4];
#pragma unroll
        for (int i = 0; i < 4; ++i)
            af[i] = *(const bf16x8*)(ldsA + (mw + 16 * i + l15) * LDA + kg * 16);
#pragma unroll
        for (int j = 0; j < 4; ++j) {
            bf16x8 bfj = *(const bf16x8*)(ldsB + (nw + 16 * j + l15) * LDA + kg * 16);
#pragma unroll
            for (int i = 0; i < 4; ++i)
                acc[i][j] = __builtin_amdgcn_mfma_f32_16x16x32_bf16(af[i], bfj, acc[i][j], 0, 0, 0);
        }
        __syncthreads();
    }
#pragma unroll
    for (int j = 0; j < 4; ++j) {
        int col = n0 + nw + 16 * j + l15;
        float bias = bh[col];
#pragma unroll
        for (int i = 0; i < 4; ++i) {
            int rb = m0 + mw + 16 * i + kg * 4;
#pragma unroll
            for (int r = 0; r < 4; ++r)
                Xp[(size_t)(rb + r) * 1024 + col] = bf16_rne(acc[i][j][r] + bias);
        }
    }
}

// ---------------- K3: scan. Flag+ack protocol at AGENT scope (sc1 only). ------
#define SB0 __builtin_amdgcn_sched_barrier(0)
#define WAITV0 asm volatile("s_waitcnt vmcnt(0)" ::: "memory")
#define WAITV4 asm volatile("s_waitcnt vmcnt(4)" ::: "memory")

#define LDT(d, a, O) asm volatile("global_load_dwordx4 %0, %1, off offset:" #O " sc1" : "=v"(d) : "v"(a) : "memory")
#define LDU(d, a, O) asm volatile("global_load_ushort %0, %1, off offset:" #O : "=v"(d) : "v"(a) : "memory")
#define STS(a, v, O) asm volatile("global_store_short %0, %1, off offset:" #O " sc1" :: "v"(a), "v"(v) : "memory")
#define STD(a, v, O) asm volatile("global_store_dword %0, %1, off offset:" #O " sc1" :: "v"(a), "v"(v) : "memory")

// 32 x 16B h-loads: row (b0+l15), cols kg*8 + 32*n  (64B byte-stride)
#define ISSUE32H(B, A) do { \
    LDT(B[0],(A),0);     LDT(B[1],(A),64);    LDT(B[2],(A),128);   LDT(B[3],(A),192);   \
    LDT(B[4],(A),256);   LDT(B[5],(A),320);   LDT(B[6],(A),384);   LDT(B[7],(A),448);   \
    LDT(B[8],(A),512);   LDT(B[9],(A),576);   LDT(B[10],(A),640);  LDT(B[11],(A),704);  \
    LDT(B[12],(A),768);  LDT(B[13],(A),832);  LDT(B[14],(A),896);  LDT(B[15],(A),960);  \
    LDT(B[16],(A),1024); LDT(B[17],(A),1088); LDT(B[18],(A),1152); LDT(B[19],(A),1216); \
    LDT(B[20],(A),1280); LDT(B[21],(A),1344); LDT(B[22],(A),1408); LDT(B[23],(A),1472); \
    LDT(B[24],(A),1536); LDT(B[25],(A),1600); LDT(B[26],(A),1664); LDT(B[27],(A),1728); \
    LDT(B[28],(A),1792); LDT(B[29],(A),1856); LDT(B[30],(A),1920); LDT(B[31],(A),1984); } while (0)

__global__ __launch_bounds__(64, 1) void k_scan(const float* __restrict__ Whh,
                                                const unsigned short* __restrict__ Xp,
                                                unsigned short* __restrict__ hbuf, // [2][64][1024] bf16
                                                unsigned int* flags,               // [256]
                                                float* __restrict__ out) {
    const int wid = blockIdx.x;    // 0..255
    const int rt = wid >> 6, ct = wid & 63;
    const int j0 = ct * 16, b0 = rt * 16;
    const int lane = threadIdx.x;
    const int l15 = lane & 15, kg = lane >> 4;
    const int jj = j0 + l15;
    const int rbase = b0 + kg * 4;

    // W_hh column-slice in registers (round-2-proven plain loads; AGPR-eligible)
    bf16x8 w[32];
#pragma unroll
    for (int i = 0; i < 32; ++i) {
#pragma unroll
        for (int e = 0; e < 8; ++e)
            w[i][e] = (short)bf16_rne(Whh[(size_t)(i * 32 + kg * 8 + e) * 1024 + jj]);
    }

    const uint64_t fp = (uint64_t)(flags + rt * 64 + lane);   // 1 flag per lane
    const uint64_t myflag = (uint64_t)(flags + wid);
    const uint64_t hrd = (uint64_t)hbuf + (uint64_t)(b0 + l15) * 2048 + kg * 16;
    const uint64_t hwr = (uint64_t)hbuf + (uint64_t)rbase * 2048 + (uint64_t)jj * 2;
    const uint64_t xb  = (uint64_t)Xp + (uint64_t)(rbase * 1024 + jj) * 2;

    u32x4 hr[32];
    unsigned xr[4];
    float hv[4];

    for (int t = 0; t < 512; ++t) {
        // ---- wait for all 64 producers of this row group (agent-scope poll) --
        if (t > 0) {
            unsigned tt = (unsigned)t;
            for (;;) {
                unsigned f;
                asm volatile("global_load_dword %0, %1, off sc1\n\t"
                             "s_waitcnt vmcnt(0)"
                             : "=v"(f) : "v"(fp) : "memory");
                if (__all((int)(f >= tt))) break;
            }
        }
        SB0;

        // ---- issue h loads (32x16B, agent-coherent), then xp loads -----------
        const uint64_t hp = hrd + ((uint64_t)(t & 1) << 17);
        ISSUE32H(hr, hp);
        const uint64_t xa = xb + (uint64_t)t * 131072;
        LDU(xr[0], xa, 0); LDU(xr[1], xa, 2048);
        LDU(xr[2], xa + 4096, 0); LDU(xr[3], xa + 4096, 2048);

        WAITV4; SB0;                        // 32 h loads retired; xp still flying

        // ---- MFMA (round-2 exact order: 4 independent chains) ----------------
        f32x4 a0 = {0.f, 0.f, 0.f, 0.f}, a1 = {0.f, 0.f, 0.f, 0.f};
        f32x4 a2 = {0.f, 0.f, 0.f, 0.f}, a3 = {0.f, 0.f, 0.f, 0.f};
#pragma unroll
        for (int ks = 0; ks < 8; ++ks) {
            a0 = __builtin_amdgcn_mfma_f32_16x16x32_bf16(
                __builtin_bit_cast(bf16x8, hr[4 * ks + 0]), w[4 * ks + 0], a0, 0, 0, 0);
            a1 = __builtin_amdgcn_mfma_f32_16x16x32_bf16(
                __builtin_bit_cast(bf16x8, hr[4 * ks + 1]), w[4 * ks + 1], a1, 0, 0, 0);
            a2 = __builtin_amdgcn_mfma_f32_16x16x32_bf16(
                __builtin_bit_cast(bf16x8, hr[4 * ks + 2]), w[4 * ks + 2], a2, 0, 0, 0);
            a3 = __builtin_amdgcn_mfma_f32_16x16x32_bf16(
                __builtin_bit_cast(bf16x8, hr[4 * ks + 3]), w[4 * ks + 3], a3, 0, 0, 0);
        }
        f32x4 acc = (a0 + a1) + (a2 + a3);

        WAITV0; SB0;                        // xp retired (hidden under MFMAs)

        // ---- tanh ------------------------------------------------------------
        unsigned hb[4];
#pragma unroll
        for (int r = 0; r < 4; ++r) {
            float z = acc[r] + bf16tof((unsigned short)xr[r]);
            z = fminf(fmaxf(z, -15.f), 15.f);
            float e = __expf(2.f * z);
            float v = (e - 1.f) / (e + 1.f);
            hv[r] = v;
            hb[r] = (unsigned)bf16_rne(v);
        }

        // ---- publish: h stores -> clean ack -> flag (proven order) -----------
        if (t < 511) {
            const uint64_t hn = hwr + ((uint64_t)((t + 1) & 1) << 17);
            STS(hn, hb[0], 0); STS(hn + 2048, hb[1], 0);
            STS(hn + 4096, hb[2], 0); STS(hn + 6144, hb[3], 0);
            WAITV0;                          // only the 4 h-stores outstanding
            if (lane == 0)
                STD(myflag, (unsigned)(t + 1), 0);
        }

        // ---- out stores: off the critical path (plain cached) ----------------
#pragma unroll
        for (int r = 0; r < 4; ++r)
            out[(size_t)(t * 64 + rbase + r) * 1024 + jj] = hv[r];
    }
#pragma unroll
    for (int r = 0; r < 4; ++r)
        out[(size_t)33554432 + (size_t)(rbase + r) * 1024 + jj] = hv[r];
}

// ---------------- launcher ---------------------------------------------------
extern "C" void kernel_launch(void* const* d_in, const int* in_sizes, int n_in,
                              void* d_out, int out_size, void* d_ws, size_t ws_size,
                              hipStream_t stream) {
    const float* X   = (const float*)d_in[0];
    const float* Wxh = (const float*)d_in[1];
    const float* Whh = (const float*)d_in[2];
    const float* bh  = (const float*)d_in[3];
    float* out = (float*)d_out;
    unsigned char* ws = (unsigned char*)d_ws;

    // workspace layout (bytes), high-water 69,469,184 (round-2-proven):
    //   [0)         Wt    : 2 MB   (W_xh^T bf16)
    //   [2097152)   Xp    : 64 MB  (bf16 [T*B][H])
    //   [69206016)  hbuf  : 256 KB (bf16 [2][64][1024])
    //   [69468160)  flags : 1 KB   (u32 [256])
    unsigned short* Wt    = (unsigned short*)(ws);
    unsigned short* Xp    = (unsigned short*)(ws + 2097152);
    unsigned short* hbuf  = (unsigned short*)(ws + 69206016);
    unsigned int*   flags = (unsigned int*)(ws + 69468160);

    hipMemsetAsync(ws + 69206016, 0, 263168, stream);   // h(0)=0, flags=0
    hipLaunchKernelGGL(k_transpose, dim3(256), dim3(256), 0, stream, Wxh, Wt);
    hipLaunchKernelGGL(k_xpgemm, dim3(2048), dim3(256), 0, stream, X, Wt, bh, Xp);
    hipLaunchKernelGGL(k_scan, dim3(256), dim3(64), 0, stream, Whh, Xp, hbuf, flags, out);
}